// Round 6
// baseline (321.197 us; speedup 1.0000x reference)
//
#include <hip/hip_runtime.h>
#include <hip/hip_bf16.h>

#define Bn 8
#define Cc 64     // Cin = Cout
#define Hh 256
#define Ww 256
#define Ss 512

typedef __attribute__((ext_vector_type(8))) short short8;   // 8 bf16 (4 VGPRs)
typedef __attribute__((ext_vector_type(4))) float floatx4;  // MFMA C/D

// fp32 -> bf16 bits, round-to-nearest-even (scalar path, k_weights)
__device__ __forceinline__ unsigned f2bf_bits(float f) {
    unsigned u = __float_as_uint(f);
    return (u + 0x7FFFu + ((u >> 16) & 1u)) >> 16;
}

// two fp32 -> packed 2x bf16 (lo in low 16 bits) via v_cvt_pk_bf16_f32
__device__ __forceinline__ unsigned pack_bf2(float lo, float hi) {
    __hip_bfloat162 p = __float22bfloat162_rn(make_float2(lo, hi));
    union { __hip_bfloat162 h; unsigned u; } cv;
    cv.h = p;
    return cv.u;
}

// ---------------------------------------------------------------------------
// Kernel 1: style linear  y[b][c] = lin_b[c] + (1/sqrt(S)) * sum_s w[b,s]*lin_w[c,s]
// ---------------------------------------------------------------------------
__global__ void k_style(const float* __restrict__ w,
                        const float* __restrict__ lin_w,
                        const float* __restrict__ lin_b,
                        float* __restrict__ y) {
    int bc = blockIdx.x;          // b*64 + c
    int b = bc >> 6, c = bc & 63;
    int lane = threadIdx.x;       // 64 threads
    float acc = 0.f;
#pragma unroll
    for (int i = 0; i < Ss / 64; ++i) {
        int s = i * 64 + lane;
        acc += w[b * Ss + s] * lin_w[c * Ss + s];
    }
#pragma unroll
    for (int off = 32; off >= 1; off >>= 1) acc += __shfl_xor(acc, off, 64);
    if (lane == 0)
        y[bc] = acc * 0.04419417382415922f /* 1/sqrt(512) */ + lin_b[c];
}

// ---------------------------------------------------------------------------
// Kernel 2: modulate + demodulate; emit bf16 weights in MFMA A-fragment
// friendly layout:  wt[b][slab(2)][tap(9)][co(64)][ci_lo(32)]
// (slab = ci>>5).  A-frag load is then a single 16B global load per m-tile.
// ---------------------------------------------------------------------------
__global__ void k_weights(const float* __restrict__ conv_w,
                          const float* __restrict__ y,
                          short* __restrict__ wt) {
    int bco = blockIdx.x;          // b*64 + co
    int b = bco >> 6, co = bco & 63;
    int ci = threadIdx.x;          // 64 threads = ci
    const float conv_scale = 1.0f / 24.0f;   // 1/sqrt(64*9)
    float yv = y[b * Cc + ci] * conv_scale;
    float wv[9];
    float ss = 0.f;
#pragma unroll
    for (int k = 0; k < 9; ++k) {
        float v = conv_w[(co * Cc + ci) * 9 + k] * yv;
        wv[k] = v;
        ss += v * v;
    }
#pragma unroll
    for (int off = 32; off >= 1; off >>= 1) ss += __shfl_xor(ss, off, 64);
    float demod = rsqrtf(ss + 1e-8f);
    int s = ci >> 5, cl = ci & 31;
#pragma unroll
    for (int t = 0; t < 9; ++t)
        wt[(((b * 2 + s) * 9 + t) * Cc + co) * 32 + cl] =
            (short)f2bf_bits(wv[t] * demod);
}

// ---------------------------------------------------------------------------
// Kernel 3: implicit-GEMM conv via 9 tap-shifted GEMMs on bf16 MFMA.
//   out[co, p] = sum_t sum_ci W_t[co,ci] * x[ci, p + delta(t)]
// Block: one b, 64 co x (4h x 64w) pixel tile. Wave w -> row h0+w, 4 n-tiles
// of 16 px. K-loop: 2 ci-slabs x 9 taps, K=32 per MFMA (no padding).
// x staged fp32->bf16 into LDS [6 rows][66 cols][32 ci pad 40] (ci innermost
// so B-frag = 1x ds_read_b128). A-frags direct from L1/L2 (73 KB per b).
//
// Staging: interior cols c=1..64 are 16 ALIGNED float4 groups per (r,cp)
// row -> per thread: fixed col-group cg=tid&15, rc=tid>>4 walking +16 per
// iter (div-free incremental r/cp), 6 iterations, each 2x float4 loads
// (ci pair planes) -> 4x v_cvt_pk_bf16_f32 -> 4x ds_write_b32. Halo cols
// c=0,65 in one masked scalar iteration (tid<192). No gw bounds check on
// the vector path (w0 + cg*4 is always in [0,252]).
//
// T1 XCD-chunked swizzle (grid flattened to 2048; swz = (bid&7)*256 +
// bid/8, bijective since 2048%8==0). Each XCD owns one b; vertically
// adjacent h-tiles (sharing 2/6 fetched halo rows) become dispatch-
// adjacent on the same XCD L2 -> halo refetch becomes L2-hit.
// Loop-top barrier elided for s=0 (nothing to protect).
//
// MFMA 16x16x32 layouts (HW-verified per guide):
//   A[m=lane&15][k=quad*8+j], B[k=quad*8+j][n=lane&15],
//   D row = quad*4+reg, col = lane&15.
// ---------------------------------------------------------------------------
__global__ __launch_bounds__(256, 3) void k_mfma(
    const float* __restrict__ x,
    const short* __restrict__ wt,
    const float* __restrict__ noise,
    const float* __restrict__ nw_p,
    const float* __restrict__ act_bias,
    float* __restrict__ out) {
    __shared__ short xs[6 * 66 * 40];

    const int tid = threadIdx.x;
    const int wave = tid >> 6, lane = tid & 63;
    const int l15 = lane & 15, quad = lane >> 4;

    // T1 XCD-chunked swizzle: consecutive bid round-robin across 8 XCDs;
    // give each XCD a contiguous 256-block chunk = exactly one batch b.
    const int bid = blockIdx.x;
    const int swz = (bid & 7) * 256 + (bid >> 3);   // bijective, 2048%8==0
    const int b = swz >> 8;                          // 0..7
    const int rem = swz & 255;                       // wtile + 4*htile
    const int w0 = (rem & 3) * 64, h0 = (rem >> 2) * 4;

    // staging decomposition, fixed per thread
    const int cg = tid & 15;            // col group: c = 1 + 4*cg
    const int rc0 = tid >> 4;           // 0..15, walks +16/iter over 0..95

    floatx4 acc[4][4];   // [m-tile][n-tile]
#pragma unroll
    for (int mt = 0; mt < 4; ++mt)
#pragma unroll
        for (int nt = 0; nt < 4; ++nt)
            acc[mt][nt] = (floatx4){0.f, 0.f, 0.f, 0.f};

    for (int s = 0; s < 2; ++s) {
        if (s) __syncthreads();   // xs reuse: previous slab's readers done

        // ---- interior: 96 (r,cp) rows x 16 aligned float4 col-groups
        {
            int r = rc0, cp = 0;                 // r = rc0 % 6, cp = rc0 / 6
            if (r >= 6) { r -= 6; cp = 1; }
            if (r >= 6) { r -= 6; cp = 2; }
            const int c = 1 + cg * 4;            // 1..61
#pragma unroll
            for (int it = 0; it < 6; ++it) {
                const int gh = h0 + r - 1;
                float4 lo4 = make_float4(0.f, 0.f, 0.f, 0.f);
                float4 hi4 = make_float4(0.f, 0.f, 0.f, 0.f);
                if ((unsigned)gh < (unsigned)Hh) {
                    const float* xp = x +
                        (((size_t)(b * Cc + s * 32 + cp * 2)) << 16) +
                        gh * Ww + (w0 + cg * 4);          // 16B aligned
                    lo4 = *(const float4*)xp;
                    hi4 = *(const float4*)(xp + Hh * Ww);
                }
                const float lov[4] = {lo4.x, lo4.y, lo4.z, lo4.w};
                const float hiv[4] = {hi4.x, hi4.y, hi4.z, hi4.w};
                unsigned* dst = (unsigned*)xs + (r * 66 + c) * 20 + cp;
#pragma unroll
                for (int j = 0; j < 4; ++j)
                    dst[j * 20] = pack_bf2(lov[j], hiv[j]);
                r += 4; cp += 2;                 // rc += 16
                if (r >= 6) { r -= 6; ++cp; }
            }
        }
        // ---- halo cols c=0 and c=65: 96 rows x 2, scalar
        if (tid < 192) {
            const int side = tid & 1;
            const int rc = tid >> 1;             // 0..95
            const int hr = rc % 6, hcp = rc / 6;
            const int gh = h0 + hr - 1;
            const int gw = side ? (w0 + 64) : (w0 - 1);
            float lo = 0.f, hi = 0.f;
            if ((unsigned)gh < (unsigned)Hh && (unsigned)gw < (unsigned)Ww) {
                const float* xp = x +
                    (((size_t)(b * Cc + s * 32 + hcp * 2)) << 16) +
                    gh * Ww + gw;
                lo = xp[0];
                hi = xp[Hh * Ww];
            }
            ((unsigned*)xs)[(hr * 66 + (side ? 65 : 0)) * 20 + hcp] =
                pack_bf2(lo, hi);
        }
        __syncthreads();

        const short* wbase = wt + (size_t)((b * 2 + s) * 9) * Cc * 32;
#pragma unroll
        for (int t = 0; t < 9; ++t) {
            const int dr = t / 3, dc = t % 3;
            short8 bfr[4];
#pragma unroll
            for (int nt = 0; nt < 4; ++nt)
                bfr[nt] = *(const short8*)(xs +
                    ((wave + dr) * 66 + (nt * 16 + l15 + dc)) * 40 + quad * 8);
            short8 afr[4];
#pragma unroll
            for (int mt = 0; mt < 4; ++mt)
                afr[mt] = *(const short8*)(wbase +
                    ((t * Cc + mt * 16 + l15) * 32 + quad * 8));
#pragma unroll
            for (int mt = 0; mt < 4; ++mt)
#pragma unroll
                for (int nt = 0; nt < 4; ++nt)
                    acc[mt][nt] = __builtin_amdgcn_mfma_f32_16x16x32_bf16(
                        afr[mt], bfr[nt], acc[mt][nt], 0, 0, 0);
        }
    }

    // ---- epilogue: noise + bias + leaky_relu * sqrt(2), fp32 store
    const int h = h0 + wave;
    const float nw = nw_p[0];
    float nz[4];
#pragma unroll
    for (int nt = 0; nt < 4; ++nt)
        nz[nt] = nw * noise[((size_t)b * Hh + h) * Ww + w0 + nt * 16 + l15];
#pragma unroll
    for (int mt = 0; mt < 4; ++mt) {
#pragma unroll
        for (int reg = 0; reg < 4; ++reg) {
            int co = mt * 16 + quad * 4 + reg;
            float bias = act_bias[co];
#pragma unroll
            for (int nt = 0; nt < 4; ++nt) {
                float v = acc[mt][nt][reg] + nz[nt] + bias;
                v = (v > 0.f ? v : 0.2f * v) * 1.41421356237f;
                out[(((size_t)(b * Cc + co)) * Hh + h) * Ww + w0 + nt * 16 + l15] = v;
            }
        }
    }
}

extern "C" void kernel_launch(void* const* d_in, const int* in_sizes, int n_in,
                              void* d_out, int out_size, void* d_ws, size_t ws_size,
                              hipStream_t stream) {
    const float* x        = (const float*)d_in[0];
    const float* w        = (const float*)d_in[1];
    const float* noise    = (const float*)d_in[2];
    const float* lin_w    = (const float*)d_in[3];
    const float* lin_b    = (const float*)d_in[4];
    const float* conv_w   = (const float*)d_in[5];
    const float* nw_p     = (const float*)d_in[6];
    const float* act_bias = (const float*)d_in[7];

    float* y  = (float*)d_ws;                       // 512 floats
    short* wtb = (short*)((char*)d_ws + 4096);      // 8*2*9*64*32 bf16 = 576 KB

    k_style<<<Bn * Cc, 64, 0, stream>>>(w, lin_w, lin_b, y);
    k_weights<<<Bn * Cc, 64, 0, stream>>>(conv_w, y, wtb);

    k_mfma<<<dim3(2048, 1, 1), 256, 0, stream>>>(x, wtb, noise, nw_p, act_bias,
                                                 (float*)d_out);
}

// Round 7
// 298.809 us; speedup vs baseline: 1.0749x; 1.0749x over previous
//
#include <hip/hip_runtime.h>
#include <hip/hip_bf16.h>

#define Bn 8
#define Cc 64     // Cin = Cout
#define Hh 256
#define Ww 256
#define Ss 512

// LDS geometry (shorts): cell = 32 ci + pad10 = 42 shorts (21 u32, odd -> read
// start banks all-distinct); row = 66 cells + pad = 2778 shorts (1389 u32,
// 1389 mod 32 = 13 odd -> write lane-groups land on disjoint bank residues).
#define LCELL 42
#define LROW  2778

typedef __attribute__((ext_vector_type(8))) short short8;   // 8 bf16 (4 VGPRs)
typedef __attribute__((ext_vector_type(4))) float floatx4;  // MFMA C/D

// fp32 -> bf16 bits, round-to-nearest-even (scalar path, k_weights)
__device__ __forceinline__ unsigned f2bf_bits(float f) {
    unsigned u = __float_as_uint(f);
    return (u + 0x7FFFu + ((u >> 16) & 1u)) >> 16;
}

// two fp32 -> packed 2x bf16 (lo in low 16 bits) via v_cvt_pk_bf16_f32
__device__ __forceinline__ unsigned pack_bf2(float lo, float hi) {
    __hip_bfloat162 p = __float22bfloat162_rn(make_float2(lo, hi));
    union { __hip_bfloat162 h; unsigned u; } cv;
    cv.h = p;
    return cv.u;
}

// ---------------------------------------------------------------------------
// Kernel 1: style linear  y[b][c] = lin_b[c] + (1/sqrt(S)) * sum_s w[b,s]*lin_w[c,s]
// ---------------------------------------------------------------------------
__global__ void k_style(const float* __restrict__ w,
                        const float* __restrict__ lin_w,
                        const float* __restrict__ lin_b,
                        float* __restrict__ y) {
    int bc = blockIdx.x;          // b*64 + c
    int b = bc >> 6, c = bc & 63;
    int lane = threadIdx.x;       // 64 threads
    float acc = 0.f;
#pragma unroll
    for (int i = 0; i < Ss / 64; ++i) {
        int s = i * 64 + lane;
        acc += w[b * Ss + s] * lin_w[c * Ss + s];
    }
#pragma unroll
    for (int off = 32; off >= 1; off >>= 1) acc += __shfl_xor(acc, off, 64);
    if (lane == 0)
        y[bc] = acc * 0.04419417382415922f /* 1/sqrt(512) */ + lin_b[c];
}

// ---------------------------------------------------------------------------
// Kernel 2: modulate + demodulate; emit bf16 weights in MFMA A-fragment
// friendly layout:  wt[b][slab(2)][tap(9)][co(64)][ci_lo(32)]
// ---------------------------------------------------------------------------
__global__ void k_weights(const float* __restrict__ conv_w,
                          const float* __restrict__ y,
                          short* __restrict__ wt) {
    int bco = blockIdx.x;          // b*64 + co
    int b = bco >> 6, co = bco & 63;
    int ci = threadIdx.x;          // 64 threads = ci
    const float conv_scale = 1.0f / 24.0f;   // 1/sqrt(64*9)
    float yv = y[b * Cc + ci] * conv_scale;
    float wv[9];
    float ss = 0.f;
#pragma unroll
    for (int k = 0; k < 9; ++k) {
        float v = conv_w[(co * Cc + ci) * 9 + k] * yv;
        wv[k] = v;
        ss += v * v;
    }
#pragma unroll
    for (int off = 32; off >= 1; off >>= 1) ss += __shfl_xor(ss, off, 64);
    float demod = rsqrtf(ss + 1e-8f);
    int s = ci >> 5, cl = ci & 31;
#pragma unroll
    for (int t = 0; t < 9; ++t)
        wt[(((b * 2 + s) * 9 + t) * Cc + co) * 32 + cl] =
            (short)f2bf_bits(wv[t] * demod);
}

// ---------------------------------------------------------------------------
// Kernel 3: implicit-GEMM conv via 9 tap-shifted GEMMs on bf16 MFMA.
// R6 restructure (counter-driven: Occ 28%, MfmaUtil 10%, VALUBusy 11%,
// LDS_BANK_CONFLICT 7.9M => latency-bound at 3 waves/SIMD + 8-way LDS
// write conflicts):
//  * 512 threads = 8 waves per block, SAME 64co x 4h x 64w tile.
//    wave: wr = wave>>1 (h row), wm = wave&1 (m-half). Per wave:
//    acc[2][4] (32 AGPR vs 64), afr[2], bfr[4]. A-frag global loads per
//    block-tap unchanged (8x2 = 16); LDS B-reads double (headroom there).
//    Est ~90 total regs -> 16-24 waves/CU (vs 12).
//  * LDS re-pad: cell 21 u32 (42 shorts), row 1389 u32 (2778 shorts).
//    Write banks: (13r + cp + 20cg) mod 32 -> 4 lane-groups on disjoint
//    stride-4 residues -> <=2 lanes/bank (free). Read starts: 21*l15 mod 32
//    all distinct. Predicts BANK_CONFLICT 7.9M -> <0.5M.
//  * Staging: 512 threads, cg = tid&15 (col group), rc0 = tid>>4 in [0,31],
//    3 iters stride 32 over 96 (r,cp) rows; 2x float4 loads + 4x cvt_pk +
//    4x ds_write_b32 per iter. Halo c=0,65: tid<192 scalar pass.
//  * T1 XCD-chunked swizzle + s=0 barrier elision kept.
// MFMA 16x16x32 layouts (HW-verified): A[m=l15][k=quad*8+j],
// B[k=quad*8+j][n=l15], D row=quad*4+reg, col=l15.
// ---------------------------------------------------------------------------
__global__ __launch_bounds__(512, 4) void k_mfma(
    const float* __restrict__ x,
    const short* __restrict__ wt,
    const float* __restrict__ noise,
    const float* __restrict__ nw_p,
    const float* __restrict__ act_bias,
    float* __restrict__ out) {
    __shared__ short xs[6 * LROW];   // 33336 B

    const int tid = threadIdx.x;
    const int wave = tid >> 6, lane = tid & 63;
    const int l15 = lane & 15, quad = lane >> 4;
    const int wr = wave >> 1;        // h row 0..3
    const int wm = wave & 1;         // m-half 0..1

    // T1 XCD-chunked swizzle: each XCD gets one contiguous b.
    const int bid = blockIdx.x;
    const int swz = (bid & 7) * 256 + (bid >> 3);   // bijective, 2048%8==0
    const int b = swz >> 8;                          // 0..7
    const int rem = swz & 255;
    const int w0 = (rem & 3) * 64, h0 = (rem >> 2) * 4;

    // staging decomposition, fixed per thread
    const int cg = tid & 15;            // col group: c = 1 + 4*cg
    const int rc0 = tid >> 4;           // 0..31, walks +32/iter over 0..95

    floatx4 acc[2][4];   // [m-tile within half][n-tile]
#pragma unroll
    for (int mi = 0; mi < 2; ++mi)
#pragma unroll
        for (int nt = 0; nt < 4; ++nt)
            acc[mi][nt] = (floatx4){0.f, 0.f, 0.f, 0.f};

    for (int s = 0; s < 2; ++s) {
        if (s) __syncthreads();   // xs reuse: previous slab's readers done

        // ---- interior: 96 (r,cp) rows x 16 aligned float4 col-groups
        {
            int r = rc0, cp = 0;         // r = rc0 % 6, cp = rc0 / 6
            if (r >= 6) { r -= 6; cp = 1; }
            if (r >= 6) { r -= 6; cp = 2; }
            if (r >= 6) { r -= 6; cp = 3; }
            if (r >= 6) { r -= 6; cp = 4; }
            if (r >= 6) { r -= 6; cp = 5; }
            const int c = 1 + cg * 4;    // 1..61
#pragma unroll
            for (int it = 0; it < 3; ++it) {
                const int gh = h0 + r - 1;
                float4 lo4 = make_float4(0.f, 0.f, 0.f, 0.f);
                float4 hi4 = make_float4(0.f, 0.f, 0.f, 0.f);
                if ((unsigned)gh < (unsigned)Hh) {
                    const float* xp = x +
                        (((size_t)(b * Cc + s * 32 + cp * 2)) << 16) +
                        gh * Ww + (w0 + cg * 4);          // 16B aligned
                    lo4 = *(const float4*)xp;
                    hi4 = *(const float4*)(xp + Hh * Ww);
                }
                const float lov[4] = {lo4.x, lo4.y, lo4.z, lo4.w};
                const float hiv[4] = {hi4.x, hi4.y, hi4.z, hi4.w};
                unsigned* dst = (unsigned*)xs + r * 1389 + c * 21 + cp;
#pragma unroll
                for (int j = 0; j < 4; ++j)
                    dst[j * 21] = pack_bf2(lov[j], hiv[j]);
                r += 2; cp += 5;                 // rc += 32 (32 = 5*6+2)
                if (r >= 6) { r -= 6; ++cp; }
            }
        }
        // ---- halo cols c=0 and c=65: 96 rows x 2, scalar
        if (tid < 192) {
            const int side = tid & 1;
            const int rc = tid >> 1;             // 0..95
            const int hr = rc % 6, hcp = rc / 6;
            const int gh = h0 + hr - 1;
            const int gw = side ? (w0 + 64) : (w0 - 1);
            float lo = 0.f, hi = 0.f;
            if ((unsigned)gh < (unsigned)Hh && (unsigned)gw < (unsigned)Ww) {
                const float* xp = x +
                    (((size_t)(b * Cc + s * 32 + hcp * 2)) << 16) +
                    gh * Ww + gw;
                lo = xp[0];
                hi = xp[Hh * Ww];
            }
            ((unsigned*)xs)[hr * 1389 + (side ? 65 : 0) * 21 + hcp] =
                pack_bf2(lo, hi);
        }
        __syncthreads();

        const short* wbase = wt + (size_t)((b * 2 + s) * 9) * Cc * 32;
#pragma unroll
        for (int t = 0; t < 9; ++t) {
            const int dr = t / 3, dc = t % 3;
            short8 bfr[4];
#pragma unroll
            for (int nt = 0; nt < 4; ++nt)
                bfr[nt] = *(const short8*)(xs +
                    (wr + dr) * LROW + (nt * 16 + l15 + dc) * LCELL + quad * 8);
            short8 afr[2];
#pragma unroll
            for (int mi = 0; mi < 2; ++mi)
                afr[mi] = *(const short8*)(wbase +
                    ((t * Cc + (wm * 2 + mi) * 16 + l15) * 32 + quad * 8));
#pragma unroll
            for (int mi = 0; mi < 2; ++mi)
#pragma unroll
                for (int nt = 0; nt < 4; ++nt)
                    acc[mi][nt] = __builtin_amdgcn_mfma_f32_16x16x32_bf16(
                        afr[mi], bfr[nt], acc[mi][nt], 0, 0, 0);
        }
    }

    // ---- epilogue: noise + bias + leaky_relu * sqrt(2), fp32 store
    const int h = h0 + wr;
    const float nw = nw_p[0];
    float nz[4];
#pragma unroll
    for (int nt = 0; nt < 4; ++nt)
        nz[nt] = nw * noise[((size_t)b * Hh + h) * Ww + w0 + nt * 16 + l15];
#pragma unroll
    for (int mi = 0; mi < 2; ++mi) {
#pragma unroll
        for (int reg = 0; reg < 4; ++reg) {
            int co = (wm * 2 + mi) * 16 + quad * 4 + reg;
            float bias = act_bias[co];
#pragma unroll
            for (int nt = 0; nt < 4; ++nt) {
                float v = acc[mi][nt][reg] + nz[nt] + bias;
                v = (v > 0.f ? v : 0.2f * v) * 1.41421356237f;
                out[(((size_t)(b * Cc + co)) * Hh + h) * Ww + w0 + nt * 16 + l15] = v;
            }
        }
    }
}

extern "C" void kernel_launch(void* const* d_in, const int* in_sizes, int n_in,
                              void* d_out, int out_size, void* d_ws, size_t ws_size,
                              hipStream_t stream) {
    const float* x        = (const float*)d_in[0];
    const float* w        = (const float*)d_in[1];
    const float* noise    = (const float*)d_in[2];
    const float* lin_w    = (const float*)d_in[3];
    const float* lin_b    = (const float*)d_in[4];
    const float* conv_w   = (const float*)d_in[5];
    const float* nw_p     = (const float*)d_in[6];
    const float* act_bias = (const float*)d_in[7];

    float* y  = (float*)d_ws;                       // 512 floats
    short* wtb = (short*)((char*)d_ws + 4096);      // 8*2*9*64*32 bf16 = 576 KB

    k_style<<<Bn * Cc, 64, 0, stream>>>(w, lin_w, lin_b, y);
    k_weights<<<Bn * Cc, 64, 0, stream>>>(conv_w, y, wtb);

    k_mfma<<<dim3(2048, 1, 1), 512, 0, stream>>>(x, wtb, noise, nw_p, act_bias,
                                                 (float*)d_out);
}